// Round 1
// baseline (520.141 us; speedup 1.0000x reference)
//
#include <hip/hip_runtime.h>

// VariationalGCNEncoder: 2-layer GCN (512 -> 4 -> [2,2]), N=100k nodes, E=3.2M edges.
//
// R7: drop the per-node sort (k_part2) entirely. Bucket-granularity grouping
// (k_part1) is sufficient: aggregation runs one block per 256-node bucket with
// per-wave-private LDS accumulators (ds_add_f32), so ebuf2/nstart/ncnt and a
// full 12.8MB sort round-trip disappear. dinv comes from a cheap per-bucket
// histogram kernel. Buckets widened 128->256 (KC 782->391): shorter part1 scan,
// 2x larger (136B) coalesced writeout segments in part1.
//
//   k_zero  : bcur[b] = b*CAP
//   k_part1 : tile->LDS 2-pass bucket sort (391 buckets of 256 nodes),
//             wave-per-bucket coalesced writeout to ebuf1 (packed (s<<8)|(d&255))
//   k_dinv  : per-bucket LDS histogram of ebuf1 -> dinv = rsqrt(deg+1)
//   k_lin1  : hls = (x @ W1) * dinv[row]   (wave-per-row, float4)
//   k_agg1  : block-per-bucket LDS-atomic aggregation of hls -> relu ->
//             ts = (h@[Wmu|Wls])*dinv, coalesced float4 writeout
//   k_agg2  : same on ts -> mu, logstd -> d_out

constexpr int N_NODES = 100000;
constexpr int N_EDGES = 3200000;
constexpr int IN_CH   = 512;
constexpr int BK_SH   = 8;                       // 256 nodes per bucket
constexpr int BK_N    = 1 << BK_SH;              // 256
constexpr int KC      = (N_NODES + BK_N - 1) / BK_N;    // 391
constexpr int CAP     = 9216;                    // mean 8184, sigma~90 -> +11 sigma
constexpr int T_TILE  = 13312;                   // edges per part1 tile (52 KB LDS)
constexpr int NT_P1   = (N_EDGES + T_TILE - 1) / T_TILE;  // 241
constexpr int ACC_ST  = 5;                       // acc stride (pad: (d*5+c)%32 hits all banks)

__global__ __launch_bounds__(256) void k_zero(int* __restrict__ bcur) {
    int i = blockIdx.x * blockDim.x + threadIdx.x;
    if (i < KC) bcur[i] = i * CAP;
}

// Tile-wise bucket sort with LDS staging; coalesced global writes only.
__global__ __launch_bounds__(512) void k_part1(const int* __restrict__ src,
                                               const int* __restrict__ dst,
                                               int* __restrict__ bcur,
                                               int* __restrict__ ebuf1) {
    __shared__ int sorted[T_TILE];   // 52 KB: bucket-sorted packed edges of this tile
    __shared__ int tstart[KC];       // tile-local exclusive bucket starts
    __shared__ int cur[KC];          // pass A: histogram; pass B: ranking cursor
    __shared__ int gbase[KC];        // reserved global base per bucket
    int tid = threadIdx.x;
    int e0 = blockIdx.x * T_TILE;
    int tcnt = min(T_TILE, N_EDGES - e0);

    for (int i = tid; i < KC; i += 512) cur[i] = 0;
    __syncthreads();

    // pass A: histogram dst buckets
    for (int j = tid; j < tcnt; j += 512) {
        int d = dst[e0 + j];
        if ((unsigned)d < (unsigned)N_NODES) atomicAdd(&cur[d >> BK_SH], 1);
    }
    __syncthreads();

    // scan cur[0..KC) -> tstart (KC=391 <= 512: one entry/thread; temp in sorted[0..511])
    {
        int v = (tid < KC) ? cur[tid] : 0;
        sorted[tid] = v;
        __syncthreads();
        for (int off = 1; off < 512; off <<= 1) {
            int t = (tid >= off) ? sorted[tid - off] : 0;
            __syncthreads();
            sorted[tid] += t;
            __syncthreads();
        }
        if (tid < KC) tstart[tid] = sorted[tid] - v;
        __syncthreads();
    }

    // reserve global space per bucket; convert cur -> ranking cursor
    for (int i = tid; i < KC; i += 512) {
        int c = cur[i];
        gbase[i] = c ? atomicAdd(&bcur[i], c) : 0;
        cur[i] = tstart[i];
    }
    __syncthreads();

    // pass B: rank + scatter into LDS (packed (s<<8)|(d&255); s < 2^17)
    for (int j = tid; j < tcnt; j += 512) {
        int s = src[e0 + j], d = dst[e0 + j];
        if ((unsigned)s < (unsigned)N_NODES && (unsigned)d < (unsigned)N_NODES) {
            int b = d >> BK_SH;
            int r = atomicAdd(&cur[b], 1);
            sorted[r] = (s << BK_SH) | (d & (BK_N - 1));
        }
    }
    __syncthreads();

    // writeout: wave-per-bucket, contiguous LDS run -> contiguous global segment
    int wv = tid >> 6, ln = tid & 63;
    for (int b = wv; b < KC; b += 8) {
        int st = tstart[b];
        int c  = cur[b] - st;               // bucket count in this tile
        int gb = gbase[b];
        int avail = (b + 1) * CAP - gb;     // capacity guard (unreachable statistically)
        if (avail < c) c = max(avail, 0);
        for (int j = ln; j < c; j += 64)
            ebuf1[gb + j] = sorted[st + j];
    }
}

// Per-bucket degree histogram -> dinv. One read of ebuf1, no sort needed.
__global__ __launch_bounds__(512) void k_dinv(const int* __restrict__ bcur,
                                              const int* __restrict__ ebuf1,
                                              float* __restrict__ dinv) {
    __shared__ int hist[BK_N];
    int b = blockIdx.x, tid = threadIdx.x;
    int base = b * CAP;
    int cnt = min(bcur[b] - base, CAP);
    if (tid < BK_N) hist[tid] = 0;
    __syncthreads();
    for (int j = tid; j < cnt; j += 512)
        atomicAdd(&hist[ebuf1[base + j] & (BK_N - 1)], 1);
    __syncthreads();
    if (tid < BK_N) {
        int node = b * BK_N + tid;
        if (node < N_NODES) dinv[node] = rsqrtf((float)(hist[tid] + 1));  // +1 self loop
    }
}

// hls[row] = (x[row,:] @ W1) * dinv[row] — one wave per row, float4 loads.
__global__ __launch_bounds__(256) void k_lin1(const float* __restrict__ x,
                                              const float* __restrict__ W1,
                                              const float* __restrict__ dinv,
                                              float* __restrict__ h) {
    int wave = threadIdx.x >> 6, lane = threadIdx.x & 63;
    int row = blockIdx.x * 4 + wave;
    if (row >= N_NODES) return;
    const float4* x4 = (const float4*)(x + (size_t)row * IN_CH);
    const float4* w4 = (const float4*)W1;
    float4 acc = make_float4(0.f, 0.f, 0.f, 0.f);
#pragma unroll
    for (int j = 0; j < 2; ++j) {
        int idx = lane + 64 * j;
        float4 v = x4[idx];
        int kb = 4 * idx;
        float4 wa = w4[kb + 0], wb = w4[kb + 1], wc = w4[kb + 2], wd = w4[kb + 3];
        acc.x += v.x * wa.x + v.y * wb.x + v.z * wc.x + v.w * wd.x;
        acc.y += v.x * wa.y + v.y * wb.y + v.z * wc.y + v.w * wd.y;
        acc.z += v.x * wa.z + v.y * wb.z + v.z * wc.z + v.w * wd.z;
        acc.w += v.x * wa.w + v.y * wb.w + v.z * wc.w + v.w * wd.w;
    }
#pragma unroll
    for (int off = 32; off > 0; off >>= 1) {
        acc.x += __shfl_down(acc.x, off);
        acc.y += __shfl_down(acc.y, off);
        acc.z += __shfl_down(acc.z, off);
        acc.w += __shfl_down(acc.w, off);
    }
    if (lane == 0) {
        float di = dinv[row];
        ((float4*)h)[row] = make_float4(acc.x * di, acc.y * di, acc.z * di, acc.w * di);
    }
}

// Layer-1: block-per-bucket LDS-atomic aggregation.
// agg = dinv_d*(sum hls[s] + hls[d]); h = relu(agg+b1); ts = (h@[Wmu|Wls])*dinv_d
__global__ __launch_bounds__(512) void k_agg1(const int* __restrict__ bcur,
                                              const int* __restrict__ ebuf1,
                                              const float* __restrict__ dinv,
                                              const float* __restrict__ hls,
                                              const float* __restrict__ b1,
                                              const float* __restrict__ Wmu,
                                              const float* __restrict__ Wls,
                                              float* __restrict__ ts) {
    __shared__ float acc[8][BK_N][ACC_ST];   // 40 KB, wave-private copies
    int tid = threadIdx.x, wv = tid >> 6;
    int b = blockIdx.x;
    int base = b * CAP;
    int cnt = min(bcur[b] - base, CAP);

    float* aflat = &acc[0][0][0];
    for (int i = tid; i < 8 * BK_N * ACC_ST; i += 512) aflat[i] = 0.f;
    __syncthreads();

    const float4* g4 = (const float4*)hls;
    int j = tid;
    for (; j + 512 < cnt; j += 1024) {               // 2x unroll for latency overlap
        int e0 = ebuf1[base + j];
        int e1 = ebuf1[base + j + 512];
        float4 v0 = g4[e0 >> BK_SH];
        float4 v1 = g4[e1 >> BK_SH];
        float* a0 = acc[wv][e0 & (BK_N - 1)];
        float* a1 = acc[wv][e1 & (BK_N - 1)];
        atomicAdd(&a0[0], v0.x); atomicAdd(&a0[1], v0.y);
        atomicAdd(&a0[2], v0.z); atomicAdd(&a0[3], v0.w);
        atomicAdd(&a1[0], v1.x); atomicAdd(&a1[1], v1.y);
        atomicAdd(&a1[2], v1.z); atomicAdd(&a1[3], v1.w);
    }
    if (j < cnt) {
        int e = ebuf1[base + j];
        float4 v = g4[e >> BK_SH];
        float* a = acc[wv][e & (BK_N - 1)];
        atomicAdd(&a[0], v.x); atomicAdd(&a[1], v.y);
        atomicAdd(&a[2], v.z); atomicAdd(&a[3], v.w);
    }
    __syncthreads();

    // reduce 8 wave-copies (1024 slots, 2 per thread)
    for (int sidx = tid; sidx < BK_N * 4; sidx += 512) {
        int nd = sidx >> 2, c = sidx & 3;
        float s = acc[0][nd][c];
#pragma unroll
        for (int k = 1; k < 8; ++k) s += acc[k][nd][c];
        acc[0][nd][c] = s;
    }
    __syncthreads();

    if (tid < BK_N) {
        int node = b * BK_N + tid;
        if (node < N_NODES) {
            float di = dinv[node];
            float4 self = g4[node];
            float h0 = fmaxf((acc[0][tid][0] + self.x) * di + b1[0], 0.f);
            float h1 = fmaxf((acc[0][tid][1] + self.y) * di + b1[1], 0.f);
            float h2 = fmaxf((acc[0][tid][2] + self.z) * di + b1[2], 0.f);
            float h3 = fmaxf((acc[0][tid][3] + self.w) * di + b1[3], 0.f);
            float4 o;
            o.x = (h0 * Wmu[0] + h1 * Wmu[2] + h2 * Wmu[4] + h3 * Wmu[6]) * di;
            o.y = (h0 * Wmu[1] + h1 * Wmu[3] + h2 * Wmu[5] + h3 * Wmu[7]) * di;
            o.z = (h0 * Wls[0] + h1 * Wls[2] + h2 * Wls[4] + h3 * Wls[6]) * di;
            o.w = (h0 * Wls[1] + h1 * Wls[3] + h2 * Wls[5] + h3 * Wls[7]) * di;
            ((float4*)ts)[node] = o;
        }
    }
}

// Layer-2 aggregation on ts -> mu (out[0..2N)), logstd (out[2N..4N)).
__global__ __launch_bounds__(512) void k_agg2(const int* __restrict__ bcur,
                                              const int* __restrict__ ebuf1,
                                              const float* __restrict__ dinv,
                                              const float* __restrict__ ts,
                                              const float* __restrict__ bmu,
                                              const float* __restrict__ bls,
                                              float* __restrict__ out) {
    __shared__ float acc[8][BK_N][ACC_ST];   // 40 KB
    int tid = threadIdx.x, wv = tid >> 6;
    int b = blockIdx.x;
    int base = b * CAP;
    int cnt = min(bcur[b] - base, CAP);

    float* aflat = &acc[0][0][0];
    for (int i = tid; i < 8 * BK_N * ACC_ST; i += 512) aflat[i] = 0.f;
    __syncthreads();

    const float4* g4 = (const float4*)ts;
    int j = tid;
    for (; j + 512 < cnt; j += 1024) {
        int e0 = ebuf1[base + j];
        int e1 = ebuf1[base + j + 512];
        float4 v0 = g4[e0 >> BK_SH];
        float4 v1 = g4[e1 >> BK_SH];
        float* a0 = acc[wv][e0 & (BK_N - 1)];
        float* a1 = acc[wv][e1 & (BK_N - 1)];
        atomicAdd(&a0[0], v0.x); atomicAdd(&a0[1], v0.y);
        atomicAdd(&a0[2], v0.z); atomicAdd(&a0[3], v0.w);
        atomicAdd(&a1[0], v1.x); atomicAdd(&a1[1], v1.y);
        atomicAdd(&a1[2], v1.z); atomicAdd(&a1[3], v1.w);
    }
    if (j < cnt) {
        int e = ebuf1[base + j];
        float4 v = g4[e >> BK_SH];
        float* a = acc[wv][e & (BK_N - 1)];
        atomicAdd(&a[0], v.x); atomicAdd(&a[1], v.y);
        atomicAdd(&a[2], v.z); atomicAdd(&a[3], v.w);
    }
    __syncthreads();

    for (int sidx = tid; sidx < BK_N * 4; sidx += 512) {
        int nd = sidx >> 2, c = sidx & 3;
        float s = acc[0][nd][c];
#pragma unroll
        for (int k = 1; k < 8; ++k) s += acc[k][nd][c];
        acc[0][nd][c] = s;
    }
    __syncthreads();

    if (tid < BK_N) {
        int node = b * BK_N + tid;
        if (node < N_NODES) {
            float di = dinv[node];
            float4 self = g4[node];
            float2 mu = make_float2((acc[0][tid][0] + self.x) * di + bmu[0],
                                    (acc[0][tid][1] + self.y) * di + bmu[1]);
            float2 ls = make_float2((acc[0][tid][2] + self.z) * di + bls[0],
                                    (acc[0][tid][3] + self.w) * di + bls[1]);
            ((float2*)out)[node] = mu;
            ((float2*)(out + 2 * N_NODES))[node] = ls;
        }
    }
}

extern "C" void kernel_launch(void* const* d_in, const int* in_sizes, int n_in,
                              void* d_out, int out_size, void* d_ws, size_t ws_size,
                              hipStream_t stream) {
    const float* x    = (const float*)d_in[0];
    const int*   ei   = (const int*)d_in[1];    // [2, E] int32: src row then dst row
    const float* W1   = (const float*)d_in[2];
    const float* b1   = (const float*)d_in[3];
    const float* Wmu  = (const float*)d_in[4];
    const float* bmu  = (const float*)d_in[5];
    const float* Wls  = (const float*)d_in[6];
    const float* bls  = (const float*)d_in[7];
    float* out = (float*)d_out;

    const int* src = ei;
    const int* dst = ei + N_EDGES;

    // workspace layout (~18 MB)
    char* p = (char*)d_ws;
    float* dinv   = (float*)p;  p += (size_t)N_NODES * 4;
    float* hls    = (float*)p;  p += (size_t)N_NODES * 16;
    float* ts     = (float*)p;  p += (size_t)N_NODES * 16;
    int*   bcur   = (int*)p;    p += (size_t)KC * 4;
    int*   ebuf1  = (int*)p;    p += (size_t)KC * CAP * 4;   // 14.4 MB

    const int TB = 256;
    int gL = (N_NODES + 3) / 4;       // 25000

    k_zero <<<(KC + TB - 1) / TB, TB, 0, stream>>>(bcur);
    k_part1<<<NT_P1, 512, 0, stream>>>(src, dst, bcur, ebuf1);
    k_dinv <<<KC,    512, 0, stream>>>(bcur, ebuf1, dinv);
    k_lin1 <<<gL,    TB,  0, stream>>>(x, W1, dinv, hls);
    k_agg1 <<<KC,    512, 0, stream>>>(bcur, ebuf1, dinv, hls, b1, Wmu, Wls, ts);
    k_agg2 <<<KC,    512, 0, stream>>>(bcur, ebuf1, dinv, ts, bmu, bls, out);
}